// Round 7
// baseline (139.084 us; speedup 1.0000x reference)
//
#include <hip/hip_runtime.h>
#include <math.h>

// Ising-flip, round 7: round-1 scalar structure (best measured: 89us, VGPR=12,
// 77% occ) + fast float-exp decision ladder. The output needs only the boolean
// (rand < p); p itself is never stored. Ladder:
//   de<=0        -> p=1,  r<1 always        -> flip iff dropout
//   arg>=0       -> p>=1                    -> flip iff dropout   (no exp)
//   arg<=-80     -> p<=2e-35 -> flip only if r<2e-35 (-> double path, ~never)
//   else         -> pa=expf(arg) (<=1ulp); decided unless |r-pa|<=pa*1e-6
//                   (8-ulp band, 4x margin) -> double path (validated absmax=0)
// Js / de / arg numerics identical to rounds 1-6 (left-assoc adds, (2s)*Js,
// (-de)*b).

#define NB 4
#define NC 8
#define HH 1024
#define WW 1024
#define PIX (HH * WW)

__global__ __launch_bounds__(256) void sc_kernel(const float* __restrict__ x,
                                                 float* __restrict__ sc) {
    int idx = blockIdx.x * 256 + threadIdx.x;          // 0 .. NB*PIX-1
    int n   = idx >> 20;
    int pix = idx & (PIX - 1);
    const float* base = x + (size_t)n * 9 * PIX + pix;
    float s = base[0];
#pragma unroll
    for (int c = 1; c < NC; ++c) s = s + base[(size_t)c * PIX];
    sc[idx] = s;
}

__global__ __launch_bounds__(256) void ising_kernel(const float* __restrict__ x,
                                                    const float* __restrict__ rnd,
                                                    const float* __restrict__ dr,
                                                    const float* __restrict__ sc,
                                                    float* __restrict__ out) {
    int idx = blockIdx.x * 256 + threadIdx.x;
    int n   = idx >> 20;
    int pix = idx & (PIX - 1);
    int y   = pix >> 10;
    int xc  = pix & (WW - 1);

    const float* scn = sc + (size_t)n * PIX;
    int ym1 = (y - 1) & (HH - 1);
    int yp1 = (y + 1) & (HH - 1);
    int ym2 = (y - 2) & (HH - 1);
    int yp2 = (y + 2) & (HH - 1);
    int xm1 = (xc - 1) & (WW - 1);
    int xp1 = (xc + 1) & (WW - 1);
    int xm2 = (xc - 2) & (WW - 1);
    int xp2 = (xc + 2) & (WW - 1);

    int row = y << 10;
    // EXACT reference accumulation order:
    // Js = sc; +roll(y,1); +roll(y,-1); +roll(x,1); +roll(x,-1);
    //          +roll(y,2); +roll(y,-2); +roll(x,2); +roll(x,-2)
    float Js = scn[row + xc];
    Js = Js + scn[(ym1 << 10) + xc];
    Js = Js + scn[(yp1 << 10) + xc];
    Js = Js + scn[row + xm1];
    Js = Js + scn[row + xp1];
    Js = Js + scn[(ym2 << 10) + xc];
    Js = Js + scn[(yp2 << 10) + xc];
    Js = Js + scn[row + xm2];
    Js = Js + scn[row + xp2];

    const float b  = x[((size_t)n * 9 + NC) * PIX + pix];
    const bool  dm = dr[pix] > 0.5f;

    const float* xs = x   + (size_t)n * 9  * PIX + pix;
    const float* rs = rnd + (size_t)n * NC * PIX + pix;
    float*       os = out + (size_t)n * 9  * PIX + pix;

#pragma unroll
    for (int c = 0; c < NC; ++c) {
        float s = xs[(size_t)c * PIX];
        float r = rs[(size_t)c * PIX];
        float de = (2.0f * s) * Js;
        bool take;
        if (de <= 0.0f) {
            take = true;                           // p = 1, r < 1 always
        } else {
            float arg = (-de) * b;
            if (arg >= 0.0f) {
                take = true;                       // p >= 1 > r
            } else if (arg <= -80.0f) {
                // p <= 1.8e-35; only r < 2e-35 can possibly flip
                take = (r < 2e-35f) ? (r < (float)exp((double)arg)) : false;
            } else {
                float pa   = expf(arg);            // OCML, <=1 ulp
                float band = pa * 1.0e-6f;         // ~8 ulp guard band
                float diff = r - pa;
                if (fabsf(diff) > band) take = (diff < 0.0f);
                else                    take = (r < (float)exp((double)arg));
            }
        }
        bool cond = take && dm;
        os[(size_t)c * PIX] = cond ? -s : s;
    }
    os[(size_t)NC * PIX] = b;
}

extern "C" void kernel_launch(void* const* d_in, const int* in_sizes, int n_in,
                              void* d_out, int out_size, void* d_ws, size_t ws_size,
                              hipStream_t stream) {
    const float* x   = (const float*)d_in[0];
    const float* rnd = (const float*)d_in[1];
    const float* dr  = (const float*)d_in[2];
    float* out = (float*)d_out;
    float* sc  = (float*)d_ws;                     // NB*PIX*4 = 16 MiB

    const int total  = NB * PIX;
    const int blocks = total / 256;
    sc_kernel<<<blocks, 256, 0, stream>>>(x, sc);
    ising_kernel<<<blocks, 256, 0, stream>>>(x, rnd, dr, sc, out);
}

// Round 8
// 109.422 us; speedup vs baseline: 1.2711x; 1.2711x over previous
//
#include <hip/hip_runtime.h>
#include <math.h>

// Ising-flip, round 8: round-1 scalar structure (best measured memory behavior)
// + BRANCHLESS fast exp with exact rare fallback.
//   mainline: pa = __expf(arg) (v_exp_f32), band = 4e-5*pa (~7x hw-exp err),
//             take = (de<=0) || (r < pa-band)   [decided when outside band]
//   fallback: one __any(undecided) branch per channel (~0.5% of wave-channels)
//             -> (float)exp((double)arg), the comparison validated absmax=0
//             in rounds 1/5/6/7. Handles inf/denormal corners (lo=NaN or 0).
// Js / de / arg numerics identical to all passing rounds.

#define NB 4
#define NC 8
#define HH 1024
#define WW 1024
#define PIX (HH * WW)

__global__ __launch_bounds__(256) void sc_kernel(const float* __restrict__ x,
                                                 float* __restrict__ sc) {
    int idx = blockIdx.x * 256 + threadIdx.x;          // 0 .. NB*PIX-1
    int n   = idx >> 20;
    int pix = idx & (PIX - 1);
    const float* base = x + (size_t)n * 9 * PIX + pix;
    float s = base[0];
#pragma unroll
    for (int c = 1; c < NC; ++c) s = s + base[(size_t)c * PIX];
    sc[idx] = s;
}

__global__ __launch_bounds__(256) void ising_kernel(const float* __restrict__ x,
                                                    const float* __restrict__ rnd,
                                                    const float* __restrict__ dr,
                                                    const float* __restrict__ sc,
                                                    float* __restrict__ out) {
    int idx = blockIdx.x * 256 + threadIdx.x;
    int n   = idx >> 20;
    int pix = idx & (PIX - 1);
    int y   = pix >> 10;
    int xc  = pix & (WW - 1);

    const float* scn = sc + (size_t)n * PIX;
    int ym1 = (y - 1) & (HH - 1);
    int yp1 = (y + 1) & (HH - 1);
    int ym2 = (y - 2) & (HH - 1);
    int yp2 = (y + 2) & (HH - 1);
    int xm1 = (xc - 1) & (WW - 1);
    int xp1 = (xc + 1) & (WW - 1);
    int xm2 = (xc - 2) & (WW - 1);
    int xp2 = (xc + 2) & (WW - 1);

    int row = y << 10;
    // EXACT reference accumulation order:
    // Js = sc; +roll(y,1); +roll(y,-1); +roll(x,1); +roll(x,-1);
    //          +roll(y,2); +roll(y,-2); +roll(x,2); +roll(x,-2)
    float Js = scn[row + xc];
    Js = Js + scn[(ym1 << 10) + xc];
    Js = Js + scn[(yp1 << 10) + xc];
    Js = Js + scn[row + xm1];
    Js = Js + scn[row + xp1];
    Js = Js + scn[(ym2 << 10) + xc];
    Js = Js + scn[(yp2 << 10) + xc];
    Js = Js + scn[row + xm2];
    Js = Js + scn[row + xp2];

    const float b  = x[((size_t)n * 9 + NC) * PIX + pix];
    const bool  dm = dr[pix] > 0.5f;

    const float* xs = x   + (size_t)n * 9  * PIX + pix;
    const float* rs = rnd + (size_t)n * NC * PIX + pix;
    float*       os = out + (size_t)n * 9  * PIX + pix;

#pragma unroll
    for (int c = 0; c < NC; ++c) {
        float s = xs[(size_t)c * PIX];
        float r = rs[(size_t)c * PIX];
        float de  = (2.0f * s) * Js;
        float arg = (-de) * b;
        // --- branchless fast path ---
        float pa   = __expf(arg);              // v_exp_f32-based, rel err <~6e-6
        float band = pa * 4.0e-5f;             // ~7x error margin
        float lo   = pa - band;
        float hi   = pa + band;
        bool  fastlow   = r < lo;              // definitely r < p
        bool  fasthigh  = r > hi;              // definitely r > p
        bool  undecided = (de > 0.0f) && !fastlow && !fasthigh;
        bool  take;
        if (__any(undecided)) {                // rare (~0.5%/wave-channel)
            float pe = (float)exp((double)arg);
            take = (de <= 0.0f) || (undecided ? (r < pe) : fastlow);
        } else {
            take = (de <= 0.0f) || fastlow;
        }
        bool cond = take && dm;
        os[(size_t)c * PIX] = cond ? -s : s;
    }
    os[(size_t)NC * PIX] = b;
}

extern "C" void kernel_launch(void* const* d_in, const int* in_sizes, int n_in,
                              void* d_out, int out_size, void* d_ws, size_t ws_size,
                              hipStream_t stream) {
    const float* x   = (const float*)d_in[0];
    const float* rnd = (const float*)d_in[1];
    const float* dr  = (const float*)d_in[2];
    float* out = (float*)d_out;
    float* sc  = (float*)d_ws;                 // NB*PIX*4 = 16 MiB

    const int total  = NB * PIX;
    const int blocks = total / 256;
    sc_kernel<<<blocks, 256, 0, stream>>>(x, sc);
    ising_kernel<<<blocks, 256, 0, stream>>>(x, rnd, dr, sc, out);
}

// Round 10
// 108.551 us; speedup vs baseline: 1.2813x; 1.0080x over previous
//
#include <hip/hip_runtime.h>
#include <math.h>

// Ising-flip, round 9b: float4 (4 px/thread) + branchless fast exp (validated
// absmax=0) + nontemporal out-stores / rand-loads. Compile fix vs round 9:
// clang ext_vector_type(4) instead of HIP_vector_type for the nontemporal
// builtins. Numerics identical to all passing rounds.

#define NB 4
#define NC 8
#define HH 1024
#define WW 1024
#define PIX (HH * WW)

typedef float f32x4 __attribute__((ext_vector_type(4)));

__global__ __launch_bounds__(256) void sc_kernel(const float* __restrict__ x,
                                                 float* __restrict__ sc) {
    int tid = blockIdx.x * 256 + threadIdx.x;        // 0 .. NB*PIX/4-1
    int n   = tid >> 18;
    int g   = tid & ((PIX / 4) - 1);
    const float* base = x + (size_t)n * 9 * PIX + (size_t)g * 4;
    f32x4 s = *reinterpret_cast<const f32x4*>(base);
#pragma unroll
    for (int c = 1; c < NC; ++c) {
        f32x4 t = *reinterpret_cast<const f32x4*>(base + (size_t)c * PIX);
        s = s + t;
    }
    *reinterpret_cast<f32x4*>(sc + (size_t)n * PIX + (size_t)g * 4) = s;
}

__global__ __launch_bounds__(256) void ising_kernel(const float* __restrict__ x,
                                                    const float* __restrict__ rnd,
                                                    const float* __restrict__ dr,
                                                    const float* __restrict__ sc,
                                                    float* __restrict__ out) {
    int tid  = blockIdx.x * 256 + threadIdx.x;
    int n    = tid >> 18;
    int g    = tid & ((PIX / 4) - 1);
    int pix0 = g << 2;
    int y    = pix0 >> 10;
    int xc   = pix0 & (WW - 1);

    const float* scn = sc + (size_t)n * PIX;
    int ym1 = (y - 1) & (HH - 1), yp1 = (y + 1) & (HH - 1);
    int ym2 = (y - 2) & (HH - 1), yp2 = (y + 2) & (HH - 1);
    int xA  = (xc - 4) & (WW - 1);                   // aligned left quad
    int xCq = (xc + 4) & (WW - 1);                   // aligned right quad

    f32x4 rB  = *reinterpret_cast<const f32x4*>(scn + (y   << 10) + xc);
    f32x4 rA  = *reinterpret_cast<const f32x4*>(scn + (y   << 10) + xA);
    f32x4 rC  = *reinterpret_cast<const f32x4*>(scn + (y   << 10) + xCq);
    f32x4 rM1 = *reinterpret_cast<const f32x4*>(scn + (ym1 << 10) + xc);
    f32x4 rP1 = *reinterpret_cast<const f32x4*>(scn + (yp1 << 10) + xc);
    f32x4 rM2 = *reinterpret_cast<const f32x4*>(scn + (ym2 << 10) + xc);
    f32x4 rP2 = *reinterpret_cast<const f32x4*>(scn + (yp2 << 10) + xc);

    // Js per pixel, exact reference add order
    float Js[4];
#pragma unroll
    for (int i = 0; i < 4; ++i) {
        float cen  = rB[i];
        float vy1m = rM1[i], vy1p = rP1[i];
        float vy2m = rM2[i], vy2p = rP2[i];
        float vx1m = (i == 0) ? rA[3] : rB[i - 1];
        float vx1p = (i == 3) ? rC[0] : rB[i + 1];
        float vx2m = (i < 2) ? rA[2 + i] : rB[i - 2];
        float vx2p = (i < 2) ? rB[i + 2] : rC[i - 2];
        float j = cen;
        j = j + vy1m; j = j + vy1p;
        j = j + vx1m; j = j + vx1p;
        j = j + vy2m; j = j + vy2p;
        j = j + vx2m; j = j + vx2p;
        Js[i] = j;
    }

    const float* xs = x   + (size_t)n * 9  * PIX + pix0;
    const float* rs = rnd + (size_t)n * NC * PIX + pix0;
    float*       os = out + (size_t)n * 9  * PIX + pix0;

    f32x4 bv = *reinterpret_cast<const f32x4*>(xs + (size_t)NC * PIX);
    f32x4 dv = *reinterpret_cast<const f32x4*>(dr + pix0);
    bool dm[4];
#pragma unroll
    for (int i = 0; i < 4; ++i) dm[i] = dv[i] > 0.5f;

#pragma unroll
    for (int c = 0; c < NC; ++c) {
        f32x4 sv = *reinterpret_cast<const f32x4*>(xs + (size_t)c * PIX);
        f32x4 rv = __builtin_nontemporal_load(
                        reinterpret_cast<const f32x4*>(rs + (size_t)c * PIX));
        float de[4], arg[4];
        bool fastlow[4], und[4];
        bool anyund = false;
#pragma unroll
        for (int i = 0; i < 4; ++i) {
            float s = sv[i], r = rv[i];
            de[i]  = (2.0f * s) * Js[i];
            arg[i] = (-de[i]) * bv[i];
            float pa   = __expf(arg[i]);          // rel err <~6e-6
            float band = pa * 4.0e-5f;            // ~7x margin
            float lo   = pa - band;
            float hi   = pa + band;
            bool  fl = r < lo;
            bool  fh = r > hi;
            fastlow[i] = fl;
            und[i] = (de[i] > 0.0f) && !fl && !fh;
            anyund = anyund || und[i];
        }
        f32x4 o;
        if (__any(anyund)) {                      // rare exact path
#pragma unroll
            for (int i = 0; i < 4; ++i) {
                float s = sv[i], r = rv[i];
                bool take;
                if (de[i] <= 0.0f)  take = true;
                else if (und[i])    take = r < (float)exp((double)arg[i]);
                else                take = fastlow[i];
                o[i] = (take && dm[i]) ? -s : s;
            }
        } else {
#pragma unroll
            for (int i = 0; i < 4; ++i) {
                float s = sv[i];
                bool take = (de[i] <= 0.0f) || fastlow[i];
                o[i] = (take && dm[i]) ? -s : s;
            }
        }
        __builtin_nontemporal_store(o, reinterpret_cast<f32x4*>(os + (size_t)c * PIX));
    }
    __builtin_nontemporal_store(bv, reinterpret_cast<f32x4*>(os + (size_t)NC * PIX));
}

extern "C" void kernel_launch(void* const* d_in, const int* in_sizes, int n_in,
                              void* d_out, int out_size, void* d_ws, size_t ws_size,
                              hipStream_t stream) {
    const float* x   = (const float*)d_in[0];
    const float* rnd = (const float*)d_in[1];
    const float* dr  = (const float*)d_in[2];
    float* out = (float*)d_out;
    float* sc  = (float*)d_ws;                   // NB*PIX*4 = 16 MiB

    const int blocks = NB * PIX / 4 / 256;       // 4096
    sc_kernel<<<blocks, 256, 0, stream>>>(x, sc);
    ising_kernel<<<blocks, 256, 0, stream>>>(x, rnd, dr, sc, out);
}

// Round 11
// 106.360 us; speedup vs baseline: 1.3077x; 1.0206x over previous
//
#include <hip/hip_runtime.h>
#include <math.h>

// Ising-flip, round 11: float4 + rolling-register y-walk (4 rows/block,
// 1 new stencil load/row instead of 5) + branchless fast exp with exact
// rare fallback (validated absmax=0 in r1/r5/r6/r8/r10) + nontemporal
// streaming loads/stores. Numerics identical to all passing rounds:
//   sc: sequential channel sum c=0..7
//   Js: center, y-1, y+1, x-1, x+1, y-2, y+2, x-2, x+2 (left-assoc adds)
//   de=(2s)*Js ; arg=(-de)*b ; __expf band decide, else exact double exp.

#define NB 4
#define NC 8
#define HH 1024
#define WW 1024
#define PIX (HH * WW)
#define STEPS 4

typedef float f32x4 __attribute__((ext_vector_type(4)));

__global__ __launch_bounds__(256) void sc_kernel(const float* __restrict__ x,
                                                 float* __restrict__ sc) {
    int tid = blockIdx.x * 256 + threadIdx.x;        // 0 .. NB*PIX/4-1
    int n   = tid >> 18;
    int g   = tid & ((PIX / 4) - 1);
    const float* base = x + (size_t)n * 9 * PIX + (size_t)g * 4;
    f32x4 s = *reinterpret_cast<const f32x4*>(base);
#pragma unroll
    for (int c = 1; c < NC; ++c) {
        f32x4 t = *reinterpret_cast<const f32x4*>(base + (size_t)c * PIX);
        s = s + t;
    }
    *reinterpret_cast<f32x4*>(sc + (size_t)n * PIX + (size_t)g * 4) = s;
}

__global__ __launch_bounds__(256) void ising_kernel(const float* __restrict__ x,
                                                    const float* __restrict__ rnd,
                                                    const float* __restrict__ dr,
                                                    const float* __restrict__ sc,
                                                    float* __restrict__ out) {
    int bid = blockIdx.x;                            // 0 .. NB*HH/STEPS-1
    int n   = bid / (HH / STEPS);
    int y0  = (bid % (HH / STEPS)) * STEPS;
    int xc  = threadIdx.x << 2;                      // 256 thr * 4 px = full row
    int xA  = (xc - 4) & (WW - 1);
    int xC  = (xc + 4) & (WW - 1);

    const float* scn = sc + (size_t)n * PIX;
#define LDSC(row, col) (*reinterpret_cast<const f32x4*>(scn + ((((row) & (HH - 1))) << 10) + (col)))

    // rolling stencil registers: rows y-2 .. y+2 at column quad xc
    f32x4 m2 = LDSC(y0 - 2, xc);
    f32x4 m1 = LDSC(y0 - 1, xc);
    f32x4 ce = LDSC(y0,     xc);
    f32x4 p1 = LDSC(y0 + 1, xc);
    f32x4 p2 = LDSC(y0 + 2, xc);

    const float* xs = x   + (size_t)n * 9  * PIX + (y0 << 10) + xc;
    const float* rs = rnd + (size_t)n * NC * PIX + (y0 << 10) + xc;
    float*       os = out + (size_t)n * 9  * PIX + (y0 << 10) + xc;
    const float* dp = dr  + (y0 << 10) + xc;

#pragma unroll
    for (int st = 0; st < STEPS; ++st) {
        int y = y0 + st;
        f32x4 rA = LDSC(y, xA);                      // current-row side quads
        f32x4 rC = LDSC(y, xC);
        f32x4 bv = __builtin_nontemporal_load(
                       reinterpret_cast<const f32x4*>(xs + (size_t)NC * PIX));
        f32x4 dv = *reinterpret_cast<const f32x4*>(dp);

        // Js per pixel, exact reference add order
        float Js[4];
#pragma unroll
        for (int i = 0; i < 4; ++i) {
            float vx1m = (i == 0) ? rA[3] : ce[i - 1];
            float vx1p = (i == 3) ? rC[0] : ce[i + 1];
            float vx2m = (i < 2) ? rA[2 + i] : ce[i - 2];
            float vx2p = (i < 2) ? ce[i + 2] : rC[i - 2];
            float j = ce[i];
            j = j + m1[i]; j = j + p1[i];
            j = j + vx1m;  j = j + vx1p;
            j = j + m2[i]; j = j + p2[i];
            j = j + vx2m;  j = j + vx2p;
            Js[i] = j;
        }
        bool dm[4];
#pragma unroll
        for (int i = 0; i < 4; ++i) dm[i] = dv[i] > 0.5f;

#pragma unroll
        for (int c = 0; c < NC; ++c) {
            f32x4 sv = __builtin_nontemporal_load(
                           reinterpret_cast<const f32x4*>(xs + (size_t)c * PIX));
            f32x4 rv = __builtin_nontemporal_load(
                           reinterpret_cast<const f32x4*>(rs + (size_t)c * PIX));
            float de[4], arg[4];
            bool fl[4], und[4];
            bool anyund = false;
#pragma unroll
            for (int i = 0; i < 4; ++i) {
                de[i]  = (2.0f * sv[i]) * Js[i];
                arg[i] = (-de[i]) * bv[i];
                float pa   = __expf(arg[i]);         // rel err <~6e-6
                float band = pa * 4.0e-5f;           // ~7x margin
                bool  l = rv[i] < pa - band;
                bool  h = rv[i] > pa + band;
                fl[i]  = l;
                und[i] = (de[i] > 0.0f) && !l && !h;
                anyund = anyund || und[i];
            }
            f32x4 o;
            if (__any(anyund)) {                     // rare exact path
#pragma unroll
                for (int i = 0; i < 4; ++i) {
                    bool take;
                    if (de[i] <= 0.0f)  take = true;
                    else if (und[i])    take = rv[i] < (float)exp((double)arg[i]);
                    else                take = fl[i];
                    o[i] = (take && dm[i]) ? -sv[i] : sv[i];
                }
            } else {
#pragma unroll
                for (int i = 0; i < 4; ++i) {
                    bool take = (de[i] <= 0.0f) || fl[i];
                    o[i] = (take && dm[i]) ? -sv[i] : sv[i];
                }
            }
            __builtin_nontemporal_store(
                o, reinterpret_cast<f32x4*>(os + (size_t)c * PIX));
        }
        __builtin_nontemporal_store(
            bv, reinterpret_cast<f32x4*>(os + (size_t)NC * PIX));

        // roll the stencil window down one row
        if (st < STEPS - 1) {
            m2 = m1; m1 = ce; ce = p1; p1 = p2;
            p2 = LDSC(y + 3, xc);
            xs += WW; rs += WW; os += WW; dp += WW;
        }
    }
#undef LDSC
}

extern "C" void kernel_launch(void* const* d_in, const int* in_sizes, int n_in,
                              void* d_out, int out_size, void* d_ws, size_t ws_size,
                              hipStream_t stream) {
    const float* x   = (const float*)d_in[0];
    const float* rnd = (const float*)d_in[1];
    const float* dr  = (const float*)d_in[2];
    float* out = (float*)d_out;
    float* sc  = (float*)d_ws;                       // NB*PIX*4 = 16 MiB

    sc_kernel<<<NB * PIX / 4 / 256, 256, 0, stream>>>(x, sc);
    ising_kernel<<<NB * HH / STEPS, 256, 0, stream>>>(x, rnd, dr, sc, out);
}